// Round 9
// baseline (496.795 us; speedup 1.0000x reference)
//
#include <hip/hip_runtime.h>
#include <stdint.h>

#define NB 4      // batch
#define SEQ 1024  // sequence
#define DM 256    // d_model == head_dim
#define NH 8      // heads

typedef __attribute__((ext_vector_type(8))) short bf8;   // 8 bf16 (4 VGPRs)
typedef __attribute__((ext_vector_type(4))) float f4;    // MFMA accumulator

__device__ __forceinline__ unsigned short f2bf(float f) {
  union { float f; uint32_t u; } c; c.f = f;
  uint32_t u = c.u;
  return (unsigned short)((u + 0x7FFFu + ((u >> 16) & 1u)) >> 16); // RNE
}

// async global->LDS DMA, 16B per lane (m97 recipe): lds dst = base + lane*16.
__device__ __forceinline__ void gl_lds16(const unsigned short* g, short* l) {
  __builtin_amdgcn_global_load_lds(
      (const __attribute__((address_space(1))) unsigned int*)g,
      (__attribute__((address_space(3))) unsigned int*)l, 16, 0, 0);
}

// Software grid barrier (R7/R8 lesson: hipLaunchCooperativeKernel is silently
// dropped under the harness's graph capture -> output stayed zero; identical
// absmax across two layouts proved the kernel never ran).  Normal launch +
// device-scope atomic barrier instead.  Co-residency: LDS 43.3KB & VGPR<=128
// admit >=2 blocks/CU x 256 CU = 512 slots >= grid.  Spin failsafe converts
// any residency surprise into wrong-answer, not a container-killing hang.
__device__ __forceinline__ void grid_barrier(unsigned* cnt, unsigned nblk) {
  __threadfence();   // release: writeback dirty L1/L2 to IC
  __syncthreads();   // all waves of this block fenced before arrival
  if (threadIdx.x == 0) {
    atomicAdd(cnt, 1u);  // device-scope (m20)
    unsigned spins = 0;
    while (atomicAdd(cnt, 0u) < nblk) {
      __builtin_amdgcn_s_sleep(8);
      if (++spins > 10000000u) break;  // failsafe (~1s >> any legit skew)
    }
  }
  __syncthreads();
  __threadfence();   // acquire: invalidate stale clean lines before reads
}

// Phase-union LDS: max member = attn (43,264 B) -> >=2 blocks/CU.
union SMemU {
  struct { float t[32][33]; } prep;                                  //  4.2 KB
  struct { short a[128 * 64]; short b[128 * 64]; } proj;             // 32   KB
  struct { short k[2][8192]; short p[2][64][40]; float l[64]; } attn;// 43.3 KB
  struct { short a[32][136]; short b[64][136]; } oproj;              // 26.1 KB
};

// ---------------------------------------------------------------------------
// R9: fused 4-phase kernel, NORMAL launch, software grid barriers.
// Hypothesis under test: non-attn 115.5us is boundary/launch overhead (it was
// invariant to 5 structural kernel edits).  Phase bodies = proven R6/R0 code
// verbatim; Xbf de-aliased (74MiB < proven 84MiB ws).
// ---------------------------------------------------------------------------
__global__ __launch_bounds__(256, 2) void fused_kernel(
    const float* Wq, const float* Wk, const float* Wv, const float* Wo,
    const float* Q, const float* K, const float* V,
    const float* bq, const float* bk, const float* bv, const float* bo,
    unsigned short* Wt3, unsigned short* WoT, unsigned short* Xbf,
    unsigned short* q_frag, unsigned short* k_frag, unsigned short* v_frag,
    unsigned short* o_ws, float* out, unsigned* bar) {
  __shared__ alignas(16) SMemU sm;

  const int tid = threadIdx.x;
  const int bid = blockIdx.x;  // 512
  const int wid = tid >> 6, lane = tid & 63;
  const int quad = lane >> 4, l16 = lane & 15;
  const f4 z4 = {0.f, 0.f, 0.f, 0.f};

  // ==== P0: prep (R6-exact) ===============================================
  {
#pragma unroll
    for (int it = 0; it < 6; ++it) {
      const int idx = (it * 512 + bid) * 256 + tid;
      const int z = idx >> 18;
      const int r = idx & 262143;
      const float* src = (z == 0) ? Q : (z == 1) ? K : V;
      const float4 v = *(const float4*)(src + (size_t)r * 4);
      short4 s;
      s.x = (short)f2bf(v.x); s.y = (short)f2bf(v.y);
      s.z = (short)f2bf(v.z); s.w = (short)f2bf(v.w);
      *(short4*)(Xbf + (size_t)z * 1048576 + (size_t)r * 4) = s;
    }
    float (*t)[33] = sm.prep.t;
    const int tx = tid & 31, ty = tid >> 5;
    for (int tt = 0; tt < 4; ++tt) {
      const int id = bid * 4 + tt;
      const float* in;
      unsigned short* outp;
      int R, C, bx, by;
      if (id < 1536) {
        const int z = id >> 9, rem = id & 511;
        in = (z == 0) ? Wq : (z == 1) ? Wk : Wv;
        outp = Wt3 + (size_t)z * 2048 * 256;
        R = 256; C = 2048; bx = rem & 63; by = rem >> 6;
      } else {
        const int rem = id - 1536;
        in = Wo; outp = WoT;
        R = 2048; C = 256; bx = rem & 7; by = rem >> 3;
      }
      const int c0 = bx * 32, r0 = by * 32;
      __syncthreads();
#pragma unroll
      for (int i = 0; i < 4; i++) {
        int r = r0 + ty + i * 8;
        t[ty + i * 8][tx] = in[(size_t)r * C + c0 + tx];
      }
      __syncthreads();
#pragma unroll
      for (int i = 0; i < 4; i++) {
        int c = c0 + ty + i * 8;
        outp[(size_t)c * R + r0 + tx] = f2bf(t[tx][ty + i * 8]);
      }
    }
  }
  grid_barrier(bar + 0, 512);

  // ==== P1: QKV projection, BK=64 (R6-exact), 3 z-tiles per block ========
  {
    short* a_lds = sm.proj.a;
    short* b_lds = sm.proj.b;
    const int bx = bid & 31, by = bid >> 5;
    const int m0 = bx * 128, n0 = by * 128;
    const int wm = wid >> 1, wn = wid & 1;
    const int srow = lane >> 2, schunk = lane & 3;
    const int cxor = quad ^ (l16 & 3);

    for (int z = 0; z < 3; z++) {
      const unsigned short* X = Xbf + (size_t)z * 1048576;
      const unsigned short* Wt = Wt3 + (size_t)z * 524288;
      const float* bias = (z == 0) ? bq : (z == 1) ? bk : bv;

      f4 acc[4][4];
#pragma unroll
      for (int i = 0; i < 4; i++)
#pragma unroll
        for (int j = 0; j < 4; j++) acc[i][j] = z4;

      for (int ko = 0; ko < 4; ko++) {
        const int k0 = ko * 64;
#pragma unroll
        for (int jj = 0; jj < 4; jj++) {
          const int c = wid * 4 + jj;
          const int kh = c >> 3, i = c & 7;
          const int row = i * 16 + srow;
          const int sc = (schunk ^ (row & 3)) * 8;
          gl_lds16(X + (size_t)(m0 + row) * DM + k0 + kh * 32 + sc, a_lds + c * 512);
          gl_lds16(Wt + (size_t)(n0 + row) * DM + k0 + kh * 32 + sc, b_lds + c * 512);
        }
        __syncthreads();
#pragma unroll
        for (int kh = 0; kh < 2; kh++) {
          bf8 af[4], bfv[4];
#pragma unroll
          for (int mi = 0; mi < 4; mi++)
            af[mi] = *(const bf8*)(a_lds + kh * 4096 + (wm * 64 + mi * 16 + l16) * 32 + cxor * 8);
#pragma unroll
          for (int ni = 0; ni < 4; ni++)
            bfv[ni] = *(const bf8*)(b_lds + kh * 4096 + (wn * 64 + ni * 16 + l16) * 32 + cxor * 8);
          if (z < 2) {
#pragma unroll
            for (int ni = 0; ni < 4; ni++)
#pragma unroll
              for (int mi = 0; mi < 4; mi++)
                acc[ni][mi] = __builtin_amdgcn_mfma_f32_16x16x32_bf16(bfv[ni], af[mi], acc[ni][mi], 0, 0, 0);
          } else {
#pragma unroll
            for (int mi = 0; mi < 4; mi++)
#pragma unroll
              for (int ni = 0; ni < 4; ni++)
                acc[mi][ni] = __builtin_amdgcn_mfma_f32_16x16x32_bf16(af[mi], bfv[ni], acc[mi][ni], 0, 0, 0);
          }
        }
        __syncthreads();
      }

      if (z < 2) {
        const float scale = (z == 0) ? 0.0901684400f : 1.0f;
        unsigned short* dst = (z == 0) ? q_frag : k_frag;
#pragma unroll
        for (int ni = 0; ni < 4; ni++) {
          const int nb = n0 + wn * 64 + ni * 16 + quad * 4;
          const float4 b4 = *(const float4*)(bias + nb);
          const int h = nb >> 8, dd = nb & 255;
          const int dq = (dd >> 3) & 3, jh = dd & 7;
#pragma unroll
          for (int mi = 0; mi < 4; mi++) {
            const int tok = m0 + wm * 64 + mi * 16 + l16;
            const int b = tok >> 10, sr = tok & 1023;
            const size_t idx = ((size_t)(b * NH + h) * 64 + (sr >> 4)) * 4096 +
                               (size_t)(dd >> 5) * 512 + ((sr & 15) + 16 * dq) * 8 + jh;
            short4 s4;
            s4.x = (short)f2bf((acc[ni][mi][0] + b4.x) * scale);
            s4.y = (short)f2bf((acc[ni][mi][1] + b4.y) * scale);
            s4.z = (short)f2bf((acc[ni][mi][2] + b4.z) * scale);
            s4.w = (short)f2bf((acc[ni][mi][3] + b4.w) * scale);
            *(short4*)(dst + idx) = s4;
          }
        }
      } else {
#pragma unroll
        for (int ni = 0; ni < 4; ni++) {
          const int n = n0 + wn * 64 + ni * 16 + l16;
          const float bsv = bias[n];
          const int h = n >> 8, d = n & 255;
#pragma unroll
          for (int mi = 0; mi < 4; mi++) {
            const int m = m0 + wm * 64 + mi * 16 + quad * 4;
            const int b = m >> 10, sr = m & 1023;
            const size_t idx = ((size_t)(b * NH + h) * 16 + (d >> 4)) * 16384 +
                               (size_t)(sr >> 5) * 512 +
                               ((d & 15) + 16 * ((sr >> 3) & 3)) * 8 + (sr & 7);
            short4 s4;
            s4.x = (short)f2bf(acc[mi][ni][0] + bsv);
            s4.y = (short)f2bf(acc[mi][ni][1] + bsv);
            s4.z = (short)f2bf(acc[mi][ni][2] + bsv);
            s4.w = (short)f2bf(acc[mi][ni][3] + bsv);
            *(short4*)(v_frag + idx) = s4;
          }
        }
      }
    }
  }
  grid_barrier(bar + 1, 512);

  // ==== P2: flash attention v12 (R0-exact body) ===========================
  {
    short (*k_lds)[8192] = sm.attn.k;
    short (*p_lds)[64][40] = sm.attn.p;
    float* l_sh = sm.attn.l;

    const int blk = bid;
    const int g = blk & 7;
    const int qt = (blk >> 3) & 15;
    const int bh = g + 8 * (blk >> 7);
    const size_t fbase = (size_t)bh * 262144;

    bf8 qf[8];
    {
      const unsigned short* qp = q_frag + fbase + (size_t)(qt * 4 + wid) * 4096 + lane * 8;
#pragma unroll
      for (int kc = 0; kc < 8; kc++) qf[kc] = *(const bf8*)(qp + kc * 512);
    }

    f4 Oacc[4][4];
#pragma unroll
    for (int i = 0; i < 4; i++)
#pragma unroll
      for (int j = 0; j < 4; j++) Oacc[i][j] = z4;
    float lpart[4] = {0.f, 0.f, 0.f, 0.f};

    const unsigned short* kdma_src = k_frag + fbase + (size_t)wid * 2048 + lane * 8;
#pragma unroll
    for (int jj = 0; jj < 4; jj++)
      gl_lds16(kdma_src + jj * 512, &k_lds[0][wid * 2048 + jj * 512]);
    __syncthreads();

    bf8 vpre0[4], vpre1[4];
    const unsigned short* vbase_p = v_frag + fbase + (size_t)(wid * 4) * 16384 + lane * 8;

#define ATTN_STEP(T, CUR, PRV, VCUR, VPRV)                                     \
  {                                                                            \
    const int t_ = (T);                                                        \
    _Pragma("unroll")                                                          \
    for (int mi = 0; mi < 4; mi++)                                             \
      VCUR[mi] = *(const bf8*)(vbase_p + (size_t)mi * 16384 + (size_t)t_ * 512); \
    f4 Sacc[2];                                                                \
    Sacc[0] = z4; Sacc[1] = z4;                                                \
    _Pragma("unroll")                                                          \
    for (int kc = 0; kc < 8; kc++) {                                           \
      const bf8 aq = qf[kc];                                                   \
      _Pragma("unroll")                                                        \
      for (int ni = 0; ni < 2; ni++) {                                         \
        const bf8 kb = *(const bf8*)(&k_lds[CUR][(ni * 8 + kc) * 512 + lane * 8]); \
        Sacc[ni] = __builtin_amdgcn_mfma_f32_16x16x32_bf16(aq, kb, Sacc[ni], 0, 0, 0); \
      }                                                                        \
    }                                                                          \
    if (t_ < 31) {                                                             \
      _Pragma("unroll")                                                        \
      for (int jj = 0; jj < 4; jj++)                                           \
        gl_lds16(kdma_src + (size_t)(t_ + 1) * 8192 + jj * 512,                \
                 &k_lds[PRV][wid * 2048 + jj * 512]);                          \
    }                                                                          \
    if (t_ > 0) {                                                              \
      bf8 pb[4];                                                               \
      _Pragma("unroll")                                                        \
      for (int nq = 0; nq < 4; nq++)                                           \
        pb[nq] = *(const bf8*)(&p_lds[PRV][nq * 16 + l16][quad * 8]);          \
      _Pragma("unroll")                                                        \
      for (int mi = 0; mi < 4; mi++)                                           \
        _Pragma("unroll")                                                      \
        for (int nq = 0; nq < 4; nq++)                                         \
          Oacc[mi][nq] = __builtin_amdgcn_mfma_f32_16x16x32_bf16(VPRV[mi], pb[nq], Oacc[mi][nq], 0, 0, 0); \
    }                                                                          \
    _Pragma("unroll")                                                          \
    for (int reg = 0; reg < 4; reg++) {                                        \
      const int qrow = wid * 16 + quad * 4 + reg;                              \
      float s = 0.f;                                                           \
      _Pragma("unroll")                                                        \
      for (int ni = 0; ni < 2; ni++) {                                         \
        const float p = exp2f(Sacc[ni][reg]);                                  \
        s += p;                                                                \
        union { float f; uint32_t u; } c;                                      \
        c.f = p;                                                               \
        p_lds[CUR][qrow][ni * 16 + l16] = (short)((c.u + 0x8000u) >> 16);      \
      }                                                                        \
      lpart[reg] += s;                                                         \
    }                                                                          \
    __syncthreads();                                                           \
  }

    for (int tt = 0; tt < 16; tt++) {
      ATTN_STEP(tt * 2, 0, 1, vpre0, vpre1)
      ATTN_STEP(tt * 2 + 1, 1, 0, vpre1, vpre0)
    }
#undef ATTN_STEP

    {
      bf8 pb[4];
#pragma unroll
      for (int nq = 0; nq < 4; nq++)
        pb[nq] = *(const bf8*)(&p_lds[1][nq * 16 + l16][quad * 8]);
#pragma unroll
      for (int mi = 0; mi < 4; mi++)
#pragma unroll
        for (int nq = 0; nq < 4; nq++)
          Oacc[mi][nq] = __builtin_amdgcn_mfma_f32_16x16x32_bf16(vpre1[mi], pb[nq], Oacc[mi][nq], 0, 0, 0);
    }

#pragma unroll
    for (int reg = 0; reg < 4; reg++) {
      float v = lpart[reg];
      v += __shfl_xor(v, 1, 64);
      v += __shfl_xor(v, 2, 64);
      v += __shfl_xor(v, 4, 64);
      v += __shfl_xor(v, 8, 64);
      if (l16 == 0) l_sh[wid * 16 + quad * 4 + reg] = v;
    }
    __syncthreads();

    const int b = bh >> 3, h = bh & 7;
#pragma unroll
    for (int nq = 0; nq < 4; nq++) {
      const int q = nq * 16 + l16;
      const float inv = 1.f / l_sh[q];
      const size_t base = ((size_t)b * SEQ + qt * 64 + q) * (NH * DM) + h * DM + wid * 64;
#pragma unroll
      for (int mi = 0; mi < 4; mi++) {
        short4 s4;
        s4.x = (short)f2bf(Oacc[mi][nq][0] * inv);
        s4.y = (short)f2bf(Oacc[mi][nq][1] * inv);
        s4.z = (short)f2bf(Oacc[mi][nq][2] * inv);
        s4.w = (short)f2bf(Oacc[mi][nq][3] * inv);
        *(short4*)(o_ws + base + mi * 16 + quad * 4) = s4;
      }
    }
  }
  grid_barrier(bar + 2, 512);

  // ==== P3: output projection, BM=32 BN=64 BK=128 (R0-exact) ==============
  {
    short (*a_lds)[136] = sm.oproj.a;
    short (*b_lds)[136] = sm.oproj.b;
    const int bx = bid & 127, by = bid >> 7;
    const int wm = wid & 1, wn = wid >> 1;
    const int m0 = bx * 32, n0 = by * 64;

    f4 acc[2];
#pragma unroll
    for (int i = 0; i < 2; i++) acc[i] = z4;

    const int ch = tid & 15, row = tid >> 4;
    for (int ko = 0; ko < 16; ko++) {
      const int k0 = ko * 128;
#pragma unroll
      for (int rb = 0; rb < 2; rb++) {
        int r = row + rb * 16;
        *(bf8*)(&a_lds[r][ch * 8]) = *(const bf8*)(o_ws + (size_t)(m0 + r) * 2048 + k0 + ch * 8);
      }
#pragma unroll
      for (int rb = 0; rb < 4; rb++) {
        int r = row + rb * 16;
        *(bf8*)(&b_lds[r][ch * 8]) = *(const bf8*)(WoT + (size_t)(n0 + r) * 2048 + k0 + ch * 8);
      }
      __syncthreads();
#pragma unroll
      for (int kc = 0; kc < 4; kc++) {
        const bf8 af = *(const bf8*)(&a_lds[wm * 16 + l16][kc * 32 + quad * 8]);
        bf8 bfv[2];
#pragma unroll
        for (int ni = 0; ni < 2; ni++)
          bfv[ni] = *(const bf8*)(&b_lds[wn * 32 + ni * 16 + l16][kc * 32 + quad * 8]);
#pragma unroll
        for (int ni = 0; ni < 2; ni++)
          acc[ni] = __builtin_amdgcn_mfma_f32_16x16x32_bf16(af, bfv[ni], acc[ni], 0, 0, 0);
      }
      __syncthreads();
    }
#pragma unroll
    for (int ni = 0; ni < 2; ni++) {
      const int n = n0 + wn * 32 + ni * 16 + l16;
      const float bv = bo[n];
#pragma unroll
      for (int reg = 0; reg < 4; reg++) {
        const int m = m0 + wm * 16 + quad * 4 + reg;
        out[(size_t)m * DM + n] = acc[ni][reg] + bv;
      }
    }
  }
}

// ---------------------------------------------------------------------------
extern "C" void kernel_launch(void* const* d_in, const int* in_sizes, int n_in,
                              void* d_out, int out_size, void* d_ws, size_t ws_size,
                              hipStream_t stream) {
  const float* Q  = (const float*)d_in[0];
  const float* K  = (const float*)d_in[1];
  const float* V  = (const float*)d_in[2];
  const float* Wq = (const float*)d_in[3];
  const float* bq = (const float*)d_in[4];
  const float* Wk = (const float*)d_in[5];
  const float* bk = (const float*)d_in[6];
  const float* Wv = (const float*)d_in[7];
  const float* bv = (const float*)d_in[8];
  const float* Wo = (const float*)d_in[9];
  const float* bo = (const float*)d_in[10];
  float* out = (float*)d_out;

  char* ws = (char*)d_ws;
  const size_t QS = (size_t)NB * NH * SEQ * DM * 2;  // 16 MiB each
  const size_t WT = (size_t)2048 * 256 * 2;          // 1 MiB each
  unsigned short* q_frag = (unsigned short*)(ws);
  unsigned short* k_frag = (unsigned short*)(ws + QS);
  unsigned short* v_frag = (unsigned short*)(ws + 2 * QS);
  unsigned short* o_ws   = (unsigned short*)(ws + 3 * QS);        // 16 MiB
  unsigned short* Wt3 = (unsigned short*)(ws + 4 * QS);           // 3 MiB
  unsigned short* WoT = (unsigned short*)(ws + 4 * QS + 3 * WT);  // 1 MiB
  // Xbf de-aliased; layout ends at 74 MiB + 256 B (< proven 84 MiB ws_size).
  unsigned short* Xbf = (unsigned short*)(ws + 4 * QS + 4 * WT);  // 6 MiB
  unsigned* bar = (unsigned*)(ws + 4 * QS + 4 * WT + 3 * 2097152);

  hipMemsetAsync(bar, 0, 256, stream);  // zero barrier counters (capturable)
  fused_kernel<<<512, 256, 0, stream>>>(Wq, Wk, Wv, Wo, Q, K, V,
                                        bq, bk, bv, bo,
                                        Wt3, WoT, Xbf,
                                        q_frag, k_frag, v_frag,
                                        o_ws, out, bar);
}

// Round 10
// 279.212 us; speedup vs baseline: 1.7793x; 1.7793x over previous
//
#include <hip/hip_runtime.h>
#include <stdint.h>

#define NB 4      // batch
#define SEQ 1024  // sequence
#define DM 256    // d_model == head_dim
#define NH 8      // heads

typedef __attribute__((ext_vector_type(8))) short bf8;   // 8 bf16 (4 VGPRs)
typedef __attribute__((ext_vector_type(4))) float f4;    // MFMA accumulator

__device__ __forceinline__ unsigned short f2bf(float f) {
  union { float f; uint32_t u; } c; c.f = f;
  uint32_t u = c.u;
  return (unsigned short)((u + 0x7FFFu + ((u >> 16) & 1u)) >> 16); // RNE
}

// async global->LDS DMA, 16B per lane (m97 recipe): lds dst = base + lane*16.
__device__ __forceinline__ void gl_lds16(const unsigned short* g, short* l) {
  __builtin_amdgcn_global_load_lds(
      (const __attribute__((address_space(1))) unsigned int*)g,
      (__attribute__((address_space(3))) unsigned int*)l, 16, 0, 0);
}

// Fragment-major layouts (per bh slice = 262144 elems = 512 KB):
//  q_frag/k_frag: [tile16 (token/16)][dchunk (d/32)][lane64][j8]
//  v_frag:        [dtile (d/16)][kvchunk (kv/32)][lane64][j8]

// ---------------------------------------------------------------------------
// Kernel 0: prep (R6-exact).  512 fat blocks.
// ---------------------------------------------------------------------------
__global__ __launch_bounds__(256) void prep_kernel(
    const float* __restrict__ Wq, const float* __restrict__ Wk,
    const float* __restrict__ Wv, const float* __restrict__ Wo,
    const float* __restrict__ Q, const float* __restrict__ K,
    const float* __restrict__ V,
    unsigned short* __restrict__ Wt3, unsigned short* __restrict__ WoT,
    unsigned short* __restrict__ Xbf) {
  const int tid = threadIdx.x;
  const int bid = blockIdx.x;  // 512 blocks

#pragma unroll
  for (int it = 0; it < 6; ++it) {
    const int idx = (it * 512 + bid) * 256 + tid;  // 0..786431
    const int z = idx >> 18;
    const int r = idx & 262143;
    const float* src = (z == 0) ? Q : (z == 1) ? K : V;
    const float4 v = *(const float4*)(src + (size_t)r * 4);
    short4 s;
    s.x = (short)f2bf(v.x); s.y = (short)f2bf(v.y);
    s.z = (short)f2bf(v.z); s.w = (short)f2bf(v.w);
    *(short4*)(Xbf + (size_t)z * 1048576 + (size_t)r * 4) = s;
  }

  __shared__ float t[32][33];
  const int tx = tid & 31, ty = tid >> 5;
  for (int tt = 0; tt < 4; ++tt) {
    const int id = bid * 4 + tt;  // 0..2047
    const float* in;
    unsigned short* out;
    int R, C, bx, by;
    if (id < 1536) {
      const int z = id >> 9, rem = id & 511;
      in = (z == 0) ? Wq : (z == 1) ? Wk : Wv;
      out = Wt3 + (size_t)z * 2048 * 256;
      R = 256; C = 2048; bx = rem & 63; by = rem >> 6;
    } else {
      const int rem = id - 1536;
      in = Wo; out = WoT;
      R = 2048; C = 256; bx = rem & 7; by = rem >> 3;
    }
    const int c0 = bx * 32, r0 = by * 32;
    __syncthreads();
#pragma unroll
    for (int i = 0; i < 4; i++) {
      int r = r0 + ty + i * 8;
      t[ty + i * 8][tx] = in[(size_t)r * C + c0 + tx];
    }
    __syncthreads();
#pragma unroll
    for (int i = 0; i < 4; i++) {
      int c = c0 + ty + i * 8;
      out[(size_t)c * R + r0 + tx] = f2bf(t[tx][ty + i * 8]);
    }
  }
}

// ---------------------------------------------------------------------------
// Kernel 1: QKV projection GEMM, BK=64 (R5/R6-exact).
// ---------------------------------------------------------------------------
__global__ __launch_bounds__(256) void proj_kernel(
    const unsigned short* __restrict__ Xbf, const unsigned short* __restrict__ Wt3,
    const float* __restrict__ bq, const float* __restrict__ bk, const float* __restrict__ bv,
    unsigned short* __restrict__ q_frag, unsigned short* __restrict__ k_frag,
    unsigned short* __restrict__ v_frag) {
  const int z = blockIdx.z;
  const unsigned short* X = Xbf + (size_t)z * 4096 * 256;
  const unsigned short* Wt = Wt3 + (size_t)z * 2048 * 256;
  const float* bias = (z == 0) ? bq : (z == 1) ? bk : bv;

  __shared__ short a_lds[128 * 64];
  __shared__ short b_lds[128 * 64];

  const int tid = threadIdx.x;
  const int wid = tid >> 6, lane = tid & 63;
  const int quad = lane >> 4, l16 = lane & 15;
  const int wm = wid >> 1, wn = wid & 1;
  const int m0 = blockIdx.x * 128, n0 = blockIdx.y * 128;

  f4 acc[4][4];
  const f4 z4 = {0.f, 0.f, 0.f, 0.f};
#pragma unroll
  for (int i = 0; i < 4; i++)
#pragma unroll
    for (int j = 0; j < 4; j++) acc[i][j] = z4;

  const int srow = lane >> 2;
  const int schunk = lane & 3;
  const int cxor = quad ^ (l16 & 3);

  for (int ko = 0; ko < 4; ko++) {
    const int k0 = ko * 64;
#pragma unroll
    for (int jj = 0; jj < 4; jj++) {
      const int c = wid * 4 + jj;
      const int kh = c >> 3, i = c & 7;
      const int row = i * 16 + srow;
      const int sc = (schunk ^ (row & 3)) * 8;
      gl_lds16(X + (size_t)(m0 + row) * DM + k0 + kh * 32 + sc, a_lds + c * 512);
      gl_lds16(Wt + (size_t)(n0 + row) * DM + k0 + kh * 32 + sc, b_lds + c * 512);
    }
    __syncthreads();
#pragma unroll
    for (int kh = 0; kh < 2; kh++) {
      bf8 af[4], bfv[4];
#pragma unroll
      for (int mi = 0; mi < 4; mi++)
        af[mi] = *(const bf8*)(a_lds + kh * 4096 + (wm * 64 + mi * 16 + l16) * 32 + cxor * 8);
#pragma unroll
      for (int ni = 0; ni < 4; ni++)
        bfv[ni] = *(const bf8*)(b_lds + kh * 4096 + (wn * 64 + ni * 16 + l16) * 32 + cxor * 8);
      if (z < 2) {
#pragma unroll
        for (int ni = 0; ni < 4; ni++)
#pragma unroll
          for (int mi = 0; mi < 4; mi++)
            acc[ni][mi] = __builtin_amdgcn_mfma_f32_16x16x32_bf16(bfv[ni], af[mi], acc[ni][mi], 0, 0, 0);
      } else {
#pragma unroll
        for (int mi = 0; mi < 4; mi++)
#pragma unroll
          for (int ni = 0; ni < 4; ni++)
            acc[mi][ni] = __builtin_amdgcn_mfma_f32_16x16x32_bf16(af[mi], bfv[ni], acc[mi][ni], 0, 0, 0);
      }
    }
    __syncthreads();
  }

  if (z < 2) {
    // q scale folds 1/sqrt(256) AND log2(e) (softmax uses exp2 directly)
    const float scale = (z == 0) ? 0.0901684400f : 1.0f;
    unsigned short* dst = (z == 0) ? q_frag : k_frag;
#pragma unroll
    for (int ni = 0; ni < 4; ni++) {
      const int nb = n0 + wn * 64 + ni * 16 + quad * 4;
      const float4 b4 = *(const float4*)(bias + nb);
      const int h = nb >> 8, dd = nb & 255;
      const int dq = (dd >> 3) & 3, jh = dd & 7;
#pragma unroll
      for (int mi = 0; mi < 4; mi++) {
        const int tok = m0 + wm * 64 + mi * 16 + l16;
        const int b = tok >> 10, sr = tok & 1023;
        const size_t idx = ((size_t)(b * NH + h) * 64 + (sr >> 4)) * 4096 +
                           (size_t)(dd >> 5) * 512 + ((sr & 15) + 16 * dq) * 8 + jh;
        short4 s4;
        s4.x = (short)f2bf((acc[ni][mi][0] + b4.x) * scale);
        s4.y = (short)f2bf((acc[ni][mi][1] + b4.y) * scale);
        s4.z = (short)f2bf((acc[ni][mi][2] + b4.z) * scale);
        s4.w = (short)f2bf((acc[ni][mi][3] + b4.w) * scale);
        *(short4*)(dst + idx) = s4;
      }
    }
  } else {
#pragma unroll
    for (int ni = 0; ni < 4; ni++) {
      const int n = n0 + wn * 64 + ni * 16 + l16;
      const float bsv = bias[n];
      const int h = n >> 8, d = n & 255;
#pragma unroll
      for (int mi = 0; mi < 4; mi++) {
        const int m = m0 + wm * 64 + mi * 16 + quad * 4;
        const int b = m >> 10, sr = m & 1023;
        const size_t idx = ((size_t)(b * NH + h) * 16 + (d >> 4)) * 16384 +
                           (size_t)(sr >> 5) * 512 +
                           ((d & 15) + 16 * ((sr >> 3) & 3)) * 8 + (sr & 7);
        short4 s4;
        s4.x = (short)f2bf(acc[mi][ni][0] + bsv);
        s4.y = (short)f2bf(acc[mi][ni][1] + bsv);
        s4.z = (short)f2bf(acc[mi][ni][2] + bsv);
        s4.w = (short)f2bf(acc[mi][ni][3] + bsv);
        *(short4*)(v_frag + idx) = s4;
      }
    }
  }
}

// ---------------------------------------------------------------------------
// Kernel 2: flash attention v17 = v12 dataflow with SINGLE K buffer +
// register prefetch (T14).  Occupancy analysis across R0-R9: LDS 43.5/59.9/
// 70.1 KB ALL gave exactly 2 blocks/CU (occ 17-21% vs 25% ceiling) despite
// 3x43.5 < 160KB -- consistent with ~40KB LDS allocation granularity.  Every
// prior variant sat above the quantum.  v17: 16KB K (single) + 10KB P + l =
// 26.9 KB -> predicts 4+ blocks/CU, 16+ waves/CU, latency finally TLP-hidden.
// Protocol/step: load K(t+1)->16 VGPRs at top (hides under S/PV/softmax);
// barrier#1 (k_lds reads done, P visible); ds_write K(t+1); barrier#2.
// 2 barriers/step; at 4 blocks/CU independent blocks cover the stalls.
// ---------------------------------------------------------------------------
__global__ __launch_bounds__(256, 4) void attn_kernel(
    const unsigned short* __restrict__ q_frag, const unsigned short* __restrict__ k_frag,
    const unsigned short* __restrict__ v_frag, unsigned short* __restrict__ o_ws) {
  __shared__ short k_lds[8192];       // 32 kv x 256 d, SINGLE buffer (16 KB)
  __shared__ short p_lds[2][64][40];  // 2 x (64 q x 32 kv) (10 KB)
  __shared__ float l_sh[64];

  const int tid = threadIdx.x;
  const int wid = tid >> 6, lane = tid & 63;
  const int quad = lane >> 4, l16 = lane & 15;
  const int blk = blockIdx.x;
  const int g = blk & 7;                 // XCD (dispatch round-robin heuristic)
  const int qt = (blk >> 3) & 15;        // q tile (64 rows)
  const int bh = g + 8 * (blk >> 7);     // 16 same-bh blocks share one XCD
  const size_t fbase = (size_t)bh * 262144;

  // Q fragments: wave's own 16 q-rows, all 8 d-chunks (coalesced, once).
  bf8 qf[8];
  {
    const unsigned short* qp = q_frag + fbase + (size_t)(qt * 4 + wid) * 4096 + lane * 8;
#pragma unroll
    for (int kc = 0; kc < 8; kc++) qf[kc] = *(const bf8*)(qp + kc * 512);
  }

  const f4 z4 = {0.f, 0.f, 0.f, 0.f};
  f4 Oacc[4][4];  // [mi(d)][nq(q)]: d = wid*64+mi*16+quad*4+reg, q = nq*16+l16
#pragma unroll
  for (int i = 0; i < 4; i++)
#pragma unroll
    for (int j = 0; j < 4; j++) Oacc[i][j] = z4;
  float lpart[4] = {0.f, 0.f, 0.f, 0.f};

  // Per-wave K staging: global src and LDS dst are the identity mapping
  // (lds[wid*2048 + jj*512 + lane*8] = G[same]), as in the DMA version.
  const unsigned short* kdma_src = k_frag + fbase + (size_t)wid * 2048 + lane * 8;
  short* const kdst = &k_lds[wid * 2048 + lane * 8];

  // prologue: stage K(0) via regs + publish
  {
    bf8 k0r[4];
#pragma unroll
    for (int jj = 0; jj < 4; jj++) k0r[jj] = *(const bf8*)(kdma_src + jj * 512);
#pragma unroll
    for (int jj = 0; jj < 4; jj++) *(bf8*)(kdst + jj * 512) = k0r[jj];
  }
  __syncthreads();

  bf8 vpre0[4], vpre1[4];
  bf8 kpre[4];  // K(t+1) in-flight registers (16 VGPRs)
  const unsigned short* vbase_p = v_frag + fbase + (size_t)(wid * 4) * 16384 + lane * 8;

#define ATTN_STEP(T, CUR, PRV, VCUR, VPRV)                                     \
  {                                                                            \
    const int t_ = (T);                                                        \
    /* issue K(t+1) global->reg EARLY: retires at the post-barrier ds_write */ \
    if (t_ < 31) {                                                             \
      _Pragma("unroll")                                                        \
      for (int jj = 0; jj < 4; jj++)                                           \
        kpre[jj] = *(const bf8*)(kdma_src + (size_t)(t_ + 1) * 8192 + jj * 512); \
    }                                                                          \
    _Pragma("unroll")                                                          \
    for (int mi = 0; mi < 4; mi++)                                             \
      VCUR[mi] = *(const bf8*)(vbase_p + (size_t)mi * 16384 + (size_t)t_ * 512); \
    f4 Sacc[2];                                                                \
    Sacc[0] = z4; Sacc[1] = z4;                                                \
    _Pragma("unroll")                                                          \
    for (int kc = 0; kc < 8; kc++) {                                           \
      const bf8 aq = qf[kc];                                                   \
      _Pragma("unroll")                                                        \
      for (int ni = 0; ni < 2; ni++) {                                         \
        const bf8 kb = *(const bf8*)(&k_lds[(ni * 8 + kc) * 512 + lane * 8]);  \
        Sacc[ni] = __builtin_amdgcn_mfma_f32_16x16x32_bf16(aq, kb, Sacc[ni], 0, 0, 0); \
      }                                                                        \
    }                                                                          \
    if (t_ > 0) {                                                              \
      bf8 pb[4];                                                               \
      _Pragma("unroll")                                                        \
      for (int nq = 0; nq < 4; nq++)                                           \
        pb[nq] = *(const bf8*)(&p_lds[PRV][nq * 16 + l16][quad * 8]);          \
      _Pragma("unroll")                                                        \
      for (int mi = 0; mi < 4; mi++)                                           \
        _Pragma("unroll")                                                      \
        for (int nq = 0; nq < 4; nq++)                                         \
          Oacc[mi][nq] = __builtin_amdgcn_mfma_f32_16x16x32_bf16(VPRV[mi], pb[nq], Oacc[mi][nq], 0, 0, 0); \
    }                                                                          \
    _Pragma("unroll")                                                          \
    for (int reg = 0; reg < 4; reg++) {                                        \
      const int qrow = wid * 16 + quad * 4 + reg;                              \
      float s = 0.f;                                                           \
      _Pragma("unroll")                                                        \
      for (int ni = 0; ni < 2; ni++) {                                         \
        const float p = exp2f(Sacc[ni][reg]);                                  \
        s += p;                                                                \
        union { float f; uint32_t u; } c;                                      \
        c.f = p;                                                               \
        p_lds[CUR][qrow][ni * 16 + l16] = (short)((c.u + 0x8000u) >> 16);      \
      }                                                                        \
      lpart[reg] += s;                                                         \
    }                                                                          \
    __syncthreads(); /* #1: all k_lds reads done; P(t) visible */              \
    if (t_ < 31) {                                                             \
      _Pragma("unroll")                                                        \
      for (int jj = 0; jj < 4; jj++) *(bf8*)(kdst + jj * 512) = kpre[jj];      \
    }                                                                          \
    __syncthreads(); /* #2: K(t+1) visible */                                  \
  }

  for (int tt = 0; tt < 16; tt++) {
    ATTN_STEP(tt * 2, 0, 1, vpre0, vpre1)
    ATTN_STEP(tt * 2 + 1, 1, 0, vpre1, vpre0)
  }
#undef ATTN_STEP

  // ---- drain: PV(31) from p_lds[1] + vpre1 = V(31)
  {
    bf8 pb[4];
#pragma unroll
    for (int nq = 0; nq < 4; nq++)
      pb[nq] = *(const bf8*)(&p_lds[1][nq * 16 + l16][quad * 8]);
#pragma unroll
    for (int mi = 0; mi < 4; mi++)
#pragma unroll
      for (int nq = 0; nq < 4; nq++)
        Oacc[mi][nq] = __builtin_amdgcn_mfma_f32_16x16x32_bf16(vpre1[mi], pb[nq], Oacc[mi][nq], 0, 0, 0);
  }

  // ---- final l: reduce over 16 kv-col lanes (each q owned by one wave)
#pragma unroll
  for (int reg = 0; reg < 4; reg++) {
    float v = lpart[reg];
    v += __shfl_xor(v, 1, 64);
    v += __shfl_xor(v, 2, 64);
    v += __shfl_xor(v, 4, 64);
    v += __shfl_xor(v, 8, 64);
    if (l16 == 0) l_sh[wid * 16 + quad * 4 + reg] = v;
  }
  __syncthreads();

  // ---- epilogue: O^T[d][q] / l(q) -> o_ws [B,S,H*256]
  const int b = bh >> 3, h = bh & 7;
#pragma unroll
  for (int nq = 0; nq < 4; nq++) {
    const int q = nq * 16 + l16;
    const float inv = 1.f / l_sh[q];
    const size_t base = ((size_t)b * SEQ + qt * 64 + q) * (NH * DM) + h * DM + wid * 64;
#pragma unroll
    for (int mi = 0; mi < 4; mi++) {
      short4 s4;
      s4.x = (short)f2bf(Oacc[mi][nq][0] * inv);
      s4.y = (short)f2bf(Oacc[mi][nq][1] * inv);
      s4.z = (short)f2bf(Oacc[mi][nq][2] * inv);
      s4.w = (short)f2bf(Oacc[mi][nq][3] * inv);
      *(short4*)(o_ws + base + mi * 16 + quad * 4) = s4;
    }
  }
}

// ---------------------------------------------------------------------------
// Kernel 3: output projection, BK=256 (R6-exact).
// ---------------------------------------------------------------------------
__global__ __launch_bounds__(256) void outproj_kernel(
    const unsigned short* __restrict__ o_ws, const unsigned short* __restrict__ WoT,
    const float* __restrict__ bo, float* __restrict__ out) {
  __shared__ short a_lds[32][264];
  __shared__ short b_lds[64][264];

  const int tid = threadIdx.x;
  const int wid = tid >> 6, lane = tid & 63;
  const int quad = lane >> 4, l16 = lane & 15;
  const int wm = wid & 1, wn = wid >> 1;
  const int m0 = blockIdx.x * 32, n0 = blockIdx.y * 64;

  const f4 z4 = {0.f, 0.f, 0.f, 0.f};
  f4 acc[2];
#pragma unroll
  for (int i = 0; i < 2; i++) acc[i] = z4;

  const int ch = tid & 31, row = tid >> 5;
  for (int ko = 0; ko < 8; ko++) {
    const int k0 = ko * 256;
#pragma unroll
    for (int rb = 0; rb < 4; rb++) {
      int r = row + rb * 8;
      *(bf8*)(&a_lds[r][ch * 8]) = *(const bf8*)(o_ws + (size_t)(m0 + r) * 2048 + k0 + ch * 8);
    }
#pragma unroll
    for (int rb = 0; rb < 8; rb++) {
      int r = row + rb * 8;
      *(bf8*)(&b_lds[r][ch * 8]) = *(const bf8*)(WoT + (size_t)(n0 + r) * 2048 + k0 + ch * 8);
    }
    __syncthreads();
#pragma unroll
    for (int kc = 0; kc < 8; kc++) {
      const bf8 af = *(const bf8*)(&a_lds[wm * 16 + l16][kc * 32 + quad * 8]);
      bf8 bfv[2];
#pragma unroll
      for (int ni = 0; ni < 2; ni++)
        bfv[ni] = *(const bf8*)(&b_lds[wn * 32 + ni * 16 + l16][kc * 32 + quad * 8]);
#pragma unroll
      for (int ni = 0; ni < 2; ni++)
        acc[ni] = __builtin_amdgcn_mfma_f32_16x16x32_bf16(af, bfv[ni], acc[ni], 0, 0, 0);
    }
    __syncthreads();
  }
#pragma unroll
  for (int ni = 0; ni < 2; ni++) {
    const int n = n0 + wn * 32 + ni * 16 + l16;
    const float bv = bo[n];
#pragma unroll
    for (int reg = 0; reg < 4; reg++) {
      const int m = m0 + wm * 16 + quad * 4 + reg;
      out[(size_t)m * DM + n] = acc[ni][reg] + bv;
    }
  }
}

// ---------------------------------------------------------------------------
extern "C" void kernel_launch(void* const* d_in, const int* in_sizes, int n_in,
                              void* d_out, int out_size, void* d_ws, size_t ws_size,
                              hipStream_t stream) {
  const float* Q  = (const float*)d_in[0];
  const float* K  = (const float*)d_in[1];
  const float* V  = (const float*)d_in[2];
  const float* Wq = (const float*)d_in[3];
  const float* bq = (const float*)d_in[4];
  const float* Wk = (const float*)d_in[5];
  const float* bk = (const float*)d_in[6];
  const float* Wv = (const float*)d_in[7];
  const float* bv = (const float*)d_in[8];
  const float* Wo = (const float*)d_in[9];
  const float* bo = (const float*)d_in[10];
  float* out = (float*)d_out;

  char* ws = (char*)d_ws;
  const size_t QS = (size_t)NB * NH * SEQ * DM * 2;  // 16 MiB each
  unsigned short* q_frag = (unsigned short*)(ws);
  unsigned short* k_frag = (unsigned short*)(ws + QS);
  unsigned short* v_frag = (unsigned short*)(ws + 2 * QS);
  unsigned short* o_ws   = (unsigned short*)(ws + 3 * QS);
  const size_t WT = (size_t)2048 * 256 * 2;  // 1 MiB each
  unsigned short* Wt3 = (unsigned short*)(ws + 4 * QS);           // 3 MiB
  unsigned short* WoT = (unsigned short*)(ws + 4 * QS + 3 * WT);  // 1 MiB
  // Xbf (6 MiB) aliases o_ws: proj reads it before attn overwrites o_ws.
  unsigned short* Xbf = o_ws;

  prep_kernel<<<512, 256, 0, stream>>>(Wq, Wk, Wv, Wo, Q, K, V,
                                       Wt3, WoT, Xbf);
  proj_kernel<<<dim3(32, 16, 3), 256, 0, stream>>>(Xbf, Wt3, bq, bk, bv,
                                                   q_frag, k_frag, v_frag);
  attn_kernel<<<512, 256, 0, stream>>>(q_frag, k_frag, v_frag, o_ws);
  outproj_kernel<<<dim3(128, 4), 256, 0, stream>>>(o_ws, WoT, bo, out);
}

// Round 11
// 181.284 us; speedup vs baseline: 2.7404x; 1.5402x over previous
//
#include <hip/hip_runtime.h>
#include <stdint.h>

#define NB 4      // batch
#define SEQ 1024  // sequence
#define DM 256    // d_model == head_dim
#define NH 8      // heads

typedef __attribute__((ext_vector_type(8))) short bf8;   // 8 bf16 (4 VGPRs)
typedef __attribute__((ext_vector_type(4))) float f4;    // MFMA accumulator

__device__ __forceinline__ unsigned short f2bf(float f) {
  union { float f; uint32_t u; } c; c.f = f;
  uint32_t u = c.u;
  return (unsigned short)((u + 0x7FFFu + ((u >> 16) & 1u)) >> 16); // RNE
}

__device__ __forceinline__ float bf2f(short s) {
  union { uint32_t u; float f; } c;
  c.u = ((uint32_t)(unsigned short)s) << 16;
  return c.f;
}

// async global->LDS DMA, 16B per lane (m97 recipe): lds dst = base + lane*16.
__device__ __forceinline__ void gl_lds16(const unsigned short* g, short* l) {
  __builtin_amdgcn_global_load_lds(
      (const __attribute__((address_space(1))) unsigned int*)g,
      (__attribute__((address_space(3))) unsigned int*)l, 16, 0, 0);
}

// ---------------------------------------------------------------------------
// Kernel 0: prep (R6-exact).  512 fat blocks.
// ---------------------------------------------------------------------------
__global__ __launch_bounds__(256) void prep_kernel(
    const float* __restrict__ Wq, const float* __restrict__ Wk,
    const float* __restrict__ Wv, const float* __restrict__ Wo,
    const float* __restrict__ Q, const float* __restrict__ K,
    const float* __restrict__ V,
    unsigned short* __restrict__ Wt3, unsigned short* __restrict__ WoT,
    unsigned short* __restrict__ Xbf) {
  const int tid = threadIdx.x;
  const int bid = blockIdx.x;  // 512 blocks

#pragma unroll
  for (int it = 0; it < 6; ++it) {
    const int idx = (it * 512 + bid) * 256 + tid;  // 0..786431
    const int z = idx >> 18;
    const int r = idx & 262143;
    const float* src = (z == 0) ? Q : (z == 1) ? K : V;
    const float4 v = *(const float4*)(src + (size_t)r * 4);
    short4 s;
    s.x = (short)f2bf(v.x); s.y = (short)f2bf(v.y);
    s.z = (short)f2bf(v.z); s.w = (short)f2bf(v.w);
    *(short4*)(Xbf + (size_t)z * 1048576 + (size_t)r * 4) = s;
  }

  __shared__ float t[32][33];
  const int tx = tid & 31, ty = tid >> 5;
  for (int tt = 0; tt < 4; ++tt) {
    const int id = bid * 4 + tt;  // 0..2047
    const float* in;
    unsigned short* out;
    int R, C, bx, by;
    if (id < 1536) {
      const int z = id >> 9, rem = id & 511;
      in = (z == 0) ? Wq : (z == 1) ? Wk : Wv;
      out = Wt3 + (size_t)z * 2048 * 256;
      R = 256; C = 2048; bx = rem & 63; by = rem >> 6;
    } else {
      const int rem = id - 1536;
      in = Wo; out = WoT;
      R = 2048; C = 256; bx = rem & 7; by = rem >> 3;
    }
    const int c0 = bx * 32, r0 = by * 32;
    __syncthreads();
#pragma unroll
    for (int i = 0; i < 4; i++) {
      int r = r0 + ty + i * 8;
      t[ty + i * 8][tx] = in[(size_t)r * C + c0 + tx];
    }
    __syncthreads();
#pragma unroll
    for (int i = 0; i < 4; i++) {
      int c = c0 + ty + i * 8;
      out[(size_t)c * R + r0 + tx] = f2bf(t[tx][ty + i * 8]);
    }
  }
}

// ---------------------------------------------------------------------------
// Kernel 1: QKV projection GEMM, BK=64 (R5/R6-exact).
// ---------------------------------------------------------------------------
__global__ __launch_bounds__(256) void proj_kernel(
    const unsigned short* __restrict__ Xbf, const unsigned short* __restrict__ Wt3,
    const float* __restrict__ bq, const float* __restrict__ bk, const float* __restrict__ bv,
    unsigned short* __restrict__ q_frag, unsigned short* __restrict__ k_frag,
    unsigned short* __restrict__ v_frag) {
  const int z = blockIdx.z;
  const unsigned short* X = Xbf + (size_t)z * 4096 * 256;
  const unsigned short* Wt = Wt3 + (size_t)z * 2048 * 256;
  const float* bias = (z == 0) ? bq : (z == 1) ? bk : bv;

  __shared__ short a_lds[128 * 64];
  __shared__ short b_lds[128 * 64];

  const int tid = threadIdx.x;
  const int wid = tid >> 6, lane = tid & 63;
  const int quad = lane >> 4, l16 = lane & 15;
  const int wm = wid >> 1, wn = wid & 1;
  const int m0 = blockIdx.x * 128, n0 = blockIdx.y * 128;

  f4 acc[4][4];
  const f4 z4 = {0.f, 0.f, 0.f, 0.f};
#pragma unroll
  for (int i = 0; i < 4; i++)
#pragma unroll
    for (int j = 0; j < 4; j++) acc[i][j] = z4;

  const int srow = lane >> 2;
  const int schunk = lane & 3;
  const int cxor = quad ^ (l16 & 3);

  for (int ko = 0; ko < 4; ko++) {
    const int k0 = ko * 64;
#pragma unroll
    for (int jj = 0; jj < 4; jj++) {
      const int c = wid * 4 + jj;
      const int kh = c >> 3, i = c & 7;
      const int row = i * 16 + srow;
      const int sc = (schunk ^ (row & 3)) * 8;
      gl_lds16(X + (size_t)(m0 + row) * DM + k0 + kh * 32 + sc, a_lds + c * 512);
      gl_lds16(Wt + (size_t)(n0 + row) * DM + k0 + kh * 32 + sc, b_lds + c * 512);
    }
    __syncthreads();
#pragma unroll
    for (int kh = 0; kh < 2; kh++) {
      bf8 af[4], bfv[4];
#pragma unroll
      for (int mi = 0; mi < 4; mi++)
        af[mi] = *(const bf8*)(a_lds + kh * 4096 + (wm * 64 + mi * 16 + l16) * 32 + cxor * 8);
#pragma unroll
      for (int ni = 0; ni < 4; ni++)
        bfv[ni] = *(const bf8*)(b_lds + kh * 4096 + (wn * 64 + ni * 16 + l16) * 32 + cxor * 8);
      if (z < 2) {
#pragma unroll
        for (int ni = 0; ni < 4; ni++)
#pragma unroll
          for (int mi = 0; mi < 4; mi++)
            acc[ni][mi] = __builtin_amdgcn_mfma_f32_16x16x32_bf16(bfv[ni], af[mi], acc[ni][mi], 0, 0, 0);
      } else {
#pragma unroll
        for (int mi = 0; mi < 4; mi++)
#pragma unroll
          for (int ni = 0; ni < 4; ni++)
            acc[mi][ni] = __builtin_amdgcn_mfma_f32_16x16x32_bf16(af[mi], bfv[ni], acc[mi][ni], 0, 0, 0);
      }
    }
    __syncthreads();
  }

  if (z < 2) {
    // q scale folds 1/sqrt(256) AND log2(e) (softmax uses exp2 directly)
    const float scale = (z == 0) ? 0.0901684400f : 1.0f;
    unsigned short* dst = (z == 0) ? q_frag : k_frag;
#pragma unroll
    for (int ni = 0; ni < 4; ni++) {
      const int nb = n0 + wn * 64 + ni * 16 + quad * 4;
      const float4 b4 = *(const float4*)(bias + nb);
      const int h = nb >> 8, dd = nb & 255;
      const int dq = (dd >> 3) & 3, jh = dd & 7;
#pragma unroll
      for (int mi = 0; mi < 4; mi++) {
        const int tok = m0 + wm * 64 + mi * 16 + l16;
        const int b = tok >> 10, sr = tok & 1023;
        const size_t idx = ((size_t)(b * NH + h) * 64 + (sr >> 4)) * 4096 +
                           (size_t)(dd >> 5) * 512 + ((sr & 15) + 16 * dq) * 8 + jh;
        short4 s4;
        s4.x = (short)f2bf((acc[ni][mi][0] + b4.x) * scale);
        s4.y = (short)f2bf((acc[ni][mi][1] + b4.y) * scale);
        s4.z = (short)f2bf((acc[ni][mi][2] + b4.z) * scale);
        s4.w = (short)f2bf((acc[ni][mi][3] + b4.w) * scale);
        *(short4*)(dst + idx) = s4;
      }
    }
  } else {
#pragma unroll
    for (int ni = 0; ni < 4; ni++) {
      const int n = n0 + wn * 64 + ni * 16 + l16;
      const float bsv = bias[n];
      const int h = n >> 8, d = n & 255;
#pragma unroll
      for (int mi = 0; mi < 4; mi++) {
        const int m = m0 + wm * 64 + mi * 16 + quad * 4;
        const int b = m >> 10, sr = m & 1023;
        const size_t idx = ((size_t)(b * NH + h) * 16 + (d >> 4)) * 16384 +
                           (size_t)(sr >> 5) * 512 +
                           ((d & 15) + 16 * ((sr >> 3) & 3)) * 8 + (sr & 7);
        short4 s4;
        s4.x = (short)f2bf(acc[mi][ni][0] + bsv);
        s4.y = (short)f2bf(acc[mi][ni][1] + bsv);
        s4.z = (short)f2bf(acc[mi][ni][2] + bsv);
        s4.w = (short)f2bf(acc[mi][ni][3] + bsv);
        *(short4*)(v_frag + idx) = s4;
      }
    }
  }
}

// ---------------------------------------------------------------------------
// Kernel 2: flash attention v18 = R4's proven kv-split (grid 1024) with a
// 26.6 KB LDS footprint.  The clean occupancy test R4/v17 each half-ran:
// >2 blocks/CU needs grid>512 (kv-split) AND LDS<~32KB (granularity rounds
// 43.5->64KB; 3x64>160) AND no VGPR clamp (R10: launch_bounds(256,4) forced
// VGPR=64 -> 356MB spill).  v18: single 16KB K buffer + DMA staged per step:
//   Vload -> S -> softmax -> bar#1 (k_lds reads done; P(t) published)
//   -> DMA K(t+1) -> PV(t-1) (16 MFMAs cover the DMA) -> bar#2 (drain).
// PV touches only p_lds/regs so it legally follows bar#1.  Split epilogue
// (unnormalized O + l_part) and decode are R4-exact.  NO launch_bounds cap.
// ---------------------------------------------------------------------------
__global__ __launch_bounds__(256) void attn_kernel(
    const unsigned short* __restrict__ q_frag, const unsigned short* __restrict__ k_frag,
    const unsigned short* __restrict__ v_frag, unsigned short* __restrict__ o_p0,
    unsigned short* __restrict__ o_p1, float* __restrict__ l_part, const int split) {
  __shared__ short k_lds[8192];       // 32 kv x 256 d, SINGLE buffer (16 KB)
  __shared__ short p_lds[2][64][40];  // 2 x (64 q x 32 kv) (10 KB)

  const int tid = threadIdx.x;
  const int wid = tid >> 6, lane = tid & 63;
  const int quad = lane >> 4, l16 = lane & 15;
  const int blk = blockIdx.x;
  const int g = blk & 7;                 // XCD (dispatch round-robin heuristic)
  const int qt = (blk >> 3) & 15;        // q tile (64 rows)
  const int kvh = split ? ((blk >> 7) & 1) : 0;      // kv half
  const int bh = g + 8 * (blk >> (split ? 8 : 7));   // same-bh blocks on one XCD
  const int t0 = kvh * 16;               // first 32-kv step of this range
  const int tlast = t0 + (split ? 15 : 31);          // last step (DMA guard)
  const int nhalf = split ? 8 : 16;      // tt loop trip count
  const size_t fbase = (size_t)bh * 262144;

  // Q fragments: wave's own 16 q-rows, all 8 d-chunks (coalesced, once).
  bf8 qf[8];
  {
    const unsigned short* qp = q_frag + fbase + (size_t)(qt * 4 + wid) * 4096 + lane * 8;
#pragma unroll
    for (int kc = 0; kc < 8; kc++) qf[kc] = *(const bf8*)(qp + kc * 512);
  }

  const f4 z4 = {0.f, 0.f, 0.f, 0.f};
  f4 Oacc[4][4];  // [mi(d)][nq(q)]: d = wid*64+mi*16+quad*4+reg, q = nq*16+l16
#pragma unroll
  for (int i = 0; i < 4; i++)
#pragma unroll
    for (int j = 0; j < 4; j++) Oacc[i][j] = z4;
  float lpart[4] = {0.f, 0.f, 0.f, 0.f};

  const unsigned short* kdma_src = k_frag + fbase + (size_t)wid * 2048 + lane * 8;
  // prologue: DMA K(t0) into the single buffer
#pragma unroll
  for (int jj = 0; jj < 4; jj++)
    gl_lds16(kdma_src + (size_t)t0 * 8192 + jj * 512, &k_lds[wid * 2048 + jj * 512]);
  __syncthreads();

  bf8 vpre0[4], vpre1[4];
  const unsigned short* vbase_p = v_frag + fbase + (size_t)(wid * 4) * 16384 + lane * 8;

#define ATTN_STEP(T, CUR, PRV, VCUR, VPRV)                                     \
  {                                                                            \
    const int t_ = (T);                                                        \
    _Pragma("unroll")                                                          \
    for (int mi = 0; mi < 4; mi++)                                             \
      VCUR[mi] = *(const bf8*)(vbase_p + (size_t)mi * 16384 + (size_t)t_ * 512); \
    f4 Sacc[2];                                                                \
    Sacc[0] = z4; Sacc[1] = z4;                                                \
    _Pragma("unroll")                                                          \
    for (int kc = 0; kc < 8; kc++) {                                           \
      const bf8 aq = qf[kc];                                                   \
      _Pragma("unroll")                                                        \
      for (int ni = 0; ni < 2; ni++) {                                         \
        const bf8 kb = *(const bf8*)(&k_lds[(ni * 8 + kc) * 512 + lane * 8]);  \
        Sacc[ni] = __builtin_amdgcn_mfma_f32_16x16x32_bf16(aq, kb, Sacc[ni], 0, 0, 0); \
      }                                                                        \
    }                                                                          \
    _Pragma("unroll")                                                          \
    for (int reg = 0; reg < 4; reg++) {                                        \
      const int qrow = wid * 16 + quad * 4 + reg;                              \
      float s = 0.f;                                                           \
      _Pragma("unroll")                                                        \
      for (int ni = 0; ni < 2; ni++) {                                         \
        const float p = exp2f(Sacc[ni][reg]);                                  \
        s += p;                                                                \
        union { float f; uint32_t u; } c;                                      \
        c.f = p;                                                               \
        p_lds[CUR][qrow][ni * 16 + l16] = (short)((c.u + 0x8000u) >> 16);      \
      }                                                                        \
      lpart[reg] += s;                                                         \
    }                                                                          \
    __syncthreads(); /* #1: k_lds reads done everywhere; P(t) published */     \
    if (t_ < tlast) {                                                          \
      _Pragma("unroll")                                                        \
      for (int jj = 0; jj < 4; jj++)                                           \
        gl_lds16(kdma_src + (size_t)(t_ + 1) * 8192 + jj * 512,                \
                 &k_lds[wid * 2048 + jj * 512]);                               \
    }                                                                          \
    if (t_ > t0) {                                                             \
      bf8 pb[4];                                                               \
      _Pragma("unroll")                                                        \
      for (int nq = 0; nq < 4; nq++)                                           \
        pb[nq] = *(const bf8*)(&p_lds[PRV][nq * 16 + l16][quad * 8]);          \
      _Pragma("unroll")                                                        \
      for (int mi = 0; mi < 4; mi++)                                           \
        _Pragma("unroll")                                                      \
        for (int nq = 0; nq < 4; nq++)                                         \
          Oacc[mi][nq] = __builtin_amdgcn_mfma_f32_16x16x32_bf16(VPRV[mi], pb[nq], Oacc[mi][nq], 0, 0, 0); \
    }                                                                          \
    __syncthreads(); /* #2: DMA drained -> K(t+1) visible */                   \
  }

  for (int tt = 0; tt < nhalf; tt++) {
    ATTN_STEP(t0 + tt * 2, 0, 1, vpre0, vpre1)
    ATTN_STEP(t0 + tt * 2 + 1, 1, 0, vpre1, vpre0)
  }
#undef ATTN_STEP

  // ---- drain: PV(last) -- last step had CUR=1, VCUR=vpre1
  {
    bf8 pb[4];
#pragma unroll
    for (int nq = 0; nq < 4; nq++)
      pb[nq] = *(const bf8*)(&p_lds[1][nq * 16 + l16][quad * 8]);
#pragma unroll
    for (int mi = 0; mi < 4; mi++)
#pragma unroll
      for (int nq = 0; nq < 4; nq++)
        Oacc[mi][nq] = __builtin_amdgcn_mfma_f32_16x16x32_bf16(vpre1[mi], pb[nq], Oacc[mi][nq], 0, 0, 0);
  }

  // ---- l-half: reduce over 16 kv-col lanes, write to global (f32)
#pragma unroll
  for (int reg = 0; reg < 4; reg++) {
    float v = lpart[reg];
    v += __shfl_xor(v, 1, 64);
    v += __shfl_xor(v, 2, 64);
    v += __shfl_xor(v, 4, 64);
    v += __shfl_xor(v, 8, 64);
    if (l16 == 0) {
      const size_t lidx = (size_t)bh * 1024 + qt * 64 + wid * 16 + quad * 4 + reg;
      l_part[(size_t)kvh * 32768 + lidx] = v;
      if (!split) l_part[32768 + lidx] = v;  // fallback: both halves identical
    }
  }

  // ---- epilogue: UNNORMALIZED O^T[d][q] (bf16) -> o_p{kvh} [B,S,H*256]
  unsigned short* op = kvh ? o_p1 : o_p0;
  const int b = bh >> 3, h = bh & 7;
#pragma unroll
  for (int nq = 0; nq < 4; nq++) {
    const int q = nq * 16 + l16;
    const size_t base = ((size_t)b * SEQ + qt * 64 + q) * (NH * DM) + h * DM + wid * 64;
#pragma unroll
    for (int mi = 0; mi < 4; mi++) {
      short4 s4;
      s4.x = (short)f2bf(Oacc[mi][nq][0]);
      s4.y = (short)f2bf(Oacc[mi][nq][1]);
      s4.z = (short)f2bf(Oacc[mi][nq][2]);
      s4.w = (short)f2bf(Oacc[mi][nq][3]);
      *(short4*)(op + base + mi * 16 + quad * 4) = s4;
    }
  }
}

// ---------------------------------------------------------------------------
// Kernel 3: output projection + kv-half combine (R4-exact).  BM=32, BN=64,
// BK=128, grid (128,4).  (O0+O1)*1/(l0+l1) during a-staging; with o_p1==o_p0
// and equal l halves (fallback) this is exactly O/l.
// ---------------------------------------------------------------------------
__global__ __launch_bounds__(256) void outproj_kernel(
    const unsigned short* __restrict__ o_p0, const unsigned short* __restrict__ o_p1,
    const float* __restrict__ l_part, const unsigned short* __restrict__ WoT,
    const float* __restrict__ bo, float* __restrict__ out) {
  __shared__ short a_lds[32][136];
  __shared__ short b_lds[64][136];

  const int tid = threadIdx.x;
  const int wid = tid >> 6, lane = tid & 63;
  const int quad = lane >> 4, l16 = lane & 15;
  const int wm = wid & 1, wn = wid >> 1;
  const int m0 = blockIdx.x * 32, n0 = blockIdx.y * 64;

  const f4 z4 = {0.f, 0.f, 0.f, 0.f};
  f4 acc[2];
#pragma unroll
  for (int i = 0; i < 2; i++) acc[i] = z4;

  const int ch = tid & 15, row = tid >> 4;
  for (int ko = 0; ko < 16; ko++) {
    const int k0 = ko * 128;
    const int h = k0 >> 8;  // head: constant within this ko iteration
#pragma unroll
    for (int rb = 0; rb < 2; rb++) {
      const int r = row + rb * 16;
      const int token = m0 + r;
      const int b_ = token >> 10, sr = token & 1023;
      const size_t lidx = (size_t)(b_ * NH + h) * 1024 + sr;
      const float inv = 1.f / (l_part[lidx] + l_part[32768 + lidx]);
      const bf8 v0 = *(const bf8*)(o_p0 + (size_t)token * 2048 + k0 + ch * 8);
      const bf8 v1 = *(const bf8*)(o_p1 + (size_t)token * 2048 + k0 + ch * 8);
      bf8 s;
#pragma unroll
      for (int j = 0; j < 8; j++)
        s[j] = (short)f2bf((bf2f(v0[j]) + bf2f(v1[j])) * inv);
      *(bf8*)(&a_lds[r][ch * 8]) = s;
    }
#pragma unroll
    for (int rb = 0; rb < 4; rb++) {
      int r = row + rb * 16;
      *(bf8*)(&b_lds[r][ch * 8]) = *(const bf8*)(WoT + (size_t)(n0 + r) * 2048 + k0 + ch * 8);
    }
    __syncthreads();
#pragma unroll
    for (int kc = 0; kc < 4; kc++) {
      const bf8 af = *(const bf8*)(&a_lds[wm * 16 + l16][kc * 32 + quad * 8]);
      bf8 bfv[2];
#pragma unroll
      for (int ni = 0; ni < 2; ni++)
        bfv[ni] = *(const bf8*)(&b_lds[wn * 32 + ni * 16 + l16][kc * 32 + quad * 8]);
#pragma unroll
      for (int ni = 0; ni < 2; ni++)
        acc[ni] = __builtin_amdgcn_mfma_f32_16x16x32_bf16(af, bfv[ni], acc[ni], 0, 0, 0);
    }
    __syncthreads();
  }
#pragma unroll
  for (int ni = 0; ni < 2; ni++) {
    const int n = n0 + wn * 32 + ni * 16 + l16;
    const float bv = bo[n];
#pragma unroll
    for (int reg = 0; reg < 4; reg++) {
      const int m = m0 + wm * 16 + quad * 4 + reg;
      out[(size_t)m * DM + n] = acc[ni][reg] + bv;
    }
  }
}

// ---------------------------------------------------------------------------
extern "C" void kernel_launch(void* const* d_in, const int* in_sizes, int n_in,
                              void* d_out, int out_size, void* d_ws, size_t ws_size,
                              hipStream_t stream) {
  const float* Q  = (const float*)d_in[0];
  const float* K  = (const float*)d_in[1];
  const float* V  = (const float*)d_in[2];
  const float* Wq = (const float*)d_in[3];
  const float* bq = (const float*)d_in[4];
  const float* Wk = (const float*)d_in[5];
  const float* bk = (const float*)d_in[6];
  const float* Wv = (const float*)d_in[7];
  const float* bv = (const float*)d_in[8];
  const float* Wo = (const float*)d_in[9];
  const float* bo = (const float*)d_in[10];
  float* out = (float*)d_out;

  char* ws = (char*)d_ws;
  const size_t QS = (size_t)NB * NH * SEQ * DM * 2;  // 16 MiB each
  const size_t WT = (size_t)2048 * 256 * 2;          // 1 MiB each
  unsigned short* q_frag = (unsigned short*)(ws);
  unsigned short* k_frag = (unsigned short*)(ws + QS);
  unsigned short* v_frag = (unsigned short*)(ws + 2 * QS);
  unsigned short* o_p0   = (unsigned short*)(ws + 3 * QS);        // 16 MiB
  unsigned short* Wt3 = (unsigned short*)(ws + 4 * QS);           // 3 MiB
  unsigned short* WoT = (unsigned short*)(ws + 4 * QS + 3 * WT);  // 1 MiB
  // l_part reuses the Wt3 slot (dead after proj): 256 KiB << 3 MiB.
  float* l_part = (float*)(ws + 4 * QS);
  // kv-split takes +16 MiB only if it provably fits (R4: engaged & passed at
  // exactly this 84 MiB bound; R3's crash was l_part beyond it).
  const size_t need_split = 4 * QS + 4 * WT + QS;  // 84 MiB
  const int split = (ws_size >= need_split) ? 1 : 0;
  unsigned short* o_p1 = split ? (unsigned short*)(ws + 4 * QS + 4 * WT) : o_p0;
  // Xbf (6 MiB) aliases o_p0: proj reads it before attn overwrites o_p0.
  unsigned short* Xbf = o_p0;

  prep_kernel<<<512, 256, 0, stream>>>(Wq, Wk, Wv, Wo, Q, K, V,
                                       Wt3, WoT, Xbf);
  proj_kernel<<<dim3(32, 16, 3), 256, 0, stream>>>(Xbf, Wt3, bq, bk, bv,
                                                   q_frag, k_frag, v_frag);
  attn_kernel<<<split ? 1024 : 512, 256, 0, stream>>>(q_frag, k_frag, v_frag,
                                                      o_p0, o_p1, l_part, split);
  outproj_kernel<<<dim3(128, 4), 256, 0, stream>>>(o_p0, o_p1, l_part, WoT, bo, out);
}

// Round 12
// 165.006 us; speedup vs baseline: 3.0108x; 1.0987x over previous
//
#include <hip/hip_runtime.h>
#include <stdint.h>

#define NB 4      // batch
#define SEQ 1024  // sequence
#define DM 256    // d_model == head_dim
#define NH 8      // heads

typedef __attribute__((ext_vector_type(8))) short bf8;   // 8 bf16 (4 VGPRs)
typedef __attribute__((ext_vector_type(4))) float f4;    // MFMA accumulator

__device__ __forceinline__ unsigned short f2bf(float f) {
  union { float f; uint32_t u; } c; c.f = f;
  uint32_t u = c.u;
  return (unsigned short)((u + 0x7FFFu + ((u >> 16) & 1u)) >> 16); // RNE
}

// async global->LDS DMA, 16B per lane (m97 recipe): lds dst = base + lane*16.
__device__ __forceinline__ void gl_lds16(const unsigned short* g, short* l) {
  __builtin_amdgcn_global_load_lds(
      (const __attribute__((address_space(1))) unsigned int*)g,
      (__attribute__((address_space(3))) unsigned int*)l, 16, 0, 0);
}

// Fragment-major layouts (per bh slice = 262144 elems = 512 KB):
//  q_frag/k_frag: [tile16 (token/16)][dchunk (d/32)][lane64][j8]
//  v_frag:        [dtile (d/16)][kvchunk (kv/32)][lane64][j8]

// ---------------------------------------------------------------------------
// Kernel 0: ALL prep in one launch.  grid (1024, 7), 256 thr.  (R5-exact —
// the session-best 166.16us configuration.)
// ---------------------------------------------------------------------------
__global__ __launch_bounds__(256) void prep_kernel(
    const float* __restrict__ Wq, const float* __restrict__ Wk,
    const float* __restrict__ Wv, const float* __restrict__ Wo,
    const float* __restrict__ Q, const float* __restrict__ K,
    const float* __restrict__ V,
    unsigned short* __restrict__ Wt3, unsigned short* __restrict__ WoT,
    unsigned short* __restrict__ Xbf) {
  const int z = blockIdx.y;
  const int tid = threadIdx.x;
  if (z >= 4) {
    const float* src = (z == 4) ? Q : (z == 5) ? K : V;
    const size_t off = (size_t)blockIdx.x * 1024 + tid * 4;
    const float4 v = *(const float4*)(src + off);
    short4 s;
    s.x = (short)f2bf(v.x); s.y = (short)f2bf(v.y);
    s.z = (short)f2bf(v.z); s.w = (short)f2bf(v.w);
    *(short4*)(Xbf + (size_t)(z - 4) * 4096 * 256 + off) = s;
    return;
  }
  if (blockIdx.x >= 512) return;
  const float* in;
  unsigned short* out;
  int R, C, bx, by;
  if (z < 3) {
    in = (z == 0) ? Wq : (z == 1) ? Wk : Wv;
    out = Wt3 + (size_t)z * 2048 * 256;
    R = 256; C = 2048; bx = blockIdx.x & 63; by = blockIdx.x >> 6;
  } else {
    in = Wo; out = WoT;
    R = 2048; C = 256; bx = blockIdx.x & 7; by = blockIdx.x >> 3;
  }
  __shared__ float t[32][33];
  const int c0 = bx * 32, r0 = by * 32;
  const int tx = tid & 31, ty = tid >> 5;
#pragma unroll
  for (int i = 0; i < 4; i++) {
    int r = r0 + ty + i * 8;
    t[ty + i * 8][tx] = in[(size_t)r * C + c0 + tx];
  }
  __syncthreads();
#pragma unroll
  for (int i = 0; i < 4; i++) {
    int c = c0 + ty + i * 8;
    out[(size_t)c * R + r0 + tx] = f2bf(t[tx][ty + i * 8]);
  }
}

// ---------------------------------------------------------------------------
// Kernel 1: QKV projection GEMM, BK=64 (R5-exact).
// ---------------------------------------------------------------------------
__global__ __launch_bounds__(256) void proj_kernel(
    const unsigned short* __restrict__ Xbf, const unsigned short* __restrict__ Wt3,
    const float* __restrict__ bq, const float* __restrict__ bk, const float* __restrict__ bv,
    unsigned short* __restrict__ q_frag, unsigned short* __restrict__ k_frag,
    unsigned short* __restrict__ v_frag) {
  const int z = blockIdx.z;
  const unsigned short* X = Xbf + (size_t)z * 4096 * 256;
  const unsigned short* Wt = Wt3 + (size_t)z * 2048 * 256;
  const float* bias = (z == 0) ? bq : (z == 1) ? bk : bv;

  __shared__ short a_lds[128 * 64];  // 16 KB: 2 halves x 8 chunks x (16r x 32k)
  __shared__ short b_lds[128 * 64];

  const int tid = threadIdx.x;
  const int wid = tid >> 6, lane = tid & 63;
  const int quad = lane >> 4, l16 = lane & 15;
  const int wm = wid >> 1, wn = wid & 1;
  const int m0 = blockIdx.x * 128, n0 = blockIdx.y * 128;

  f4 acc[4][4];
  const f4 z4 = {0.f, 0.f, 0.f, 0.f};
#pragma unroll
  for (int i = 0; i < 4; i++)
#pragma unroll
    for (int j = 0; j < 4; j++) acc[i][j] = z4;

  const int srow = lane >> 2;
  const int schunk = lane & 3;
  const int cxor = quad ^ (l16 & 3);

  for (int ko = 0; ko < 4; ko++) {
    const int k0 = ko * 64;
#pragma unroll
    for (int jj = 0; jj < 4; jj++) {
      const int c = wid * 4 + jj;          // chunk 0..15
      const int kh = c >> 3, i = c & 7;    // k-half, row-chunk
      const int row = i * 16 + srow;
      const int sc = (schunk ^ (row & 3)) * 8;
      gl_lds16(X + (size_t)(m0 + row) * DM + k0 + kh * 32 + sc, a_lds + c * 512);
      gl_lds16(Wt + (size_t)(n0 + row) * DM + k0 + kh * 32 + sc, b_lds + c * 512);
    }
    __syncthreads();
#pragma unroll
    for (int kh = 0; kh < 2; kh++) {
      bf8 af[4], bfv[4];
#pragma unroll
      for (int mi = 0; mi < 4; mi++)
        af[mi] = *(const bf8*)(a_lds + kh * 4096 + (wm * 64 + mi * 16 + l16) * 32 + cxor * 8);
#pragma unroll
      for (int ni = 0; ni < 4; ni++)
        bfv[ni] = *(const bf8*)(b_lds + kh * 4096 + (wn * 64 + ni * 16 + l16) * 32 + cxor * 8);
      if (z < 2) {
#pragma unroll
        for (int ni = 0; ni < 4; ni++)
#pragma unroll
          for (int mi = 0; mi < 4; mi++)
            acc[ni][mi] = __builtin_amdgcn_mfma_f32_16x16x32_bf16(bfv[ni], af[mi], acc[ni][mi], 0, 0, 0);
      } else {
#pragma unroll
        for (int mi = 0; mi < 4; mi++)
#pragma unroll
          for (int ni = 0; ni < 4; ni++)
            acc[mi][ni] = __builtin_amdgcn_mfma_f32_16x16x32_bf16(af[mi], bfv[ni], acc[mi][ni], 0, 0, 0);
      }
    }
    __syncthreads();
  }

  if (z < 2) {
    // q scale folds 1/sqrt(256) AND log2(e) (softmax uses exp2 directly)
    const float scale = (z == 0) ? 0.0901684400f : 1.0f;
    unsigned short* dst = (z == 0) ? q_frag : k_frag;
#pragma unroll
    for (int ni = 0; ni < 4; ni++) {
      const int nb = n0 + wn * 64 + ni * 16 + quad * 4;  // 4 consecutive d
      const float4 b4 = *(const float4*)(bias + nb);
      const int h = nb >> 8, dd = nb & 255;
      const int dq = (dd >> 3) & 3, jh = dd & 7;
#pragma unroll
      for (int mi = 0; mi < 4; mi++) {
        const int tok = m0 + wm * 64 + mi * 16 + l16;
        const int b = tok >> 10, sr = tok & 1023;
        const size_t idx = ((size_t)(b * NH + h) * 64 + (sr >> 4)) * 4096 +
                           (size_t)(dd >> 5) * 512 + ((sr & 15) + 16 * dq) * 8 + jh;
        short4 s4;
        s4.x = (short)f2bf((acc[ni][mi][0] + b4.x) * scale);
        s4.y = (short)f2bf((acc[ni][mi][1] + b4.y) * scale);
        s4.z = (short)f2bf((acc[ni][mi][2] + b4.z) * scale);
        s4.w = (short)f2bf((acc[ni][mi][3] + b4.w) * scale);
        *(short4*)(dst + idx) = s4;
      }
    }
  } else {
#pragma unroll
    for (int ni = 0; ni < 4; ni++) {
      const int n = n0 + wn * 64 + ni * 16 + l16;
      const float bsv = bias[n];
      const int h = n >> 8, d = n & 255;
#pragma unroll
      for (int mi = 0; mi < 4; mi++) {
        const int m = m0 + wm * 64 + mi * 16 + quad * 4;
        const int b = m >> 10, sr = m & 1023;
        const size_t idx = ((size_t)(b * NH + h) * 16 + (d >> 4)) * 16384 +
                           (size_t)(sr >> 5) * 512 +
                           ((d & 15) + 16 * ((sr >> 3) & 3)) * 8 + (sr & 7);
        short4 s4;
        s4.x = (short)f2bf(acc[mi][ni][0] + bsv);
        s4.y = (short)f2bf(acc[mi][ni][1] + bsv);
        s4.z = (short)f2bf(acc[mi][ni][2] + bsv);
        s4.w = (short)f2bf(acc[mi][ni][3] + bsv);
        *(short4*)(v_frag + idx) = s4;
      }
    }
  }
}

// ---------------------------------------------------------------------------
// Kernel 2: flash attention v12 (R0-exact; the proven ~50us local optimum).
// Falsified levers (R1-R11): LDS-read-BW (v13), barrier vmem-drain +
// counted-wait (v14), kv-split grid occupancy (v15/v16/v18), LDS-granularity
// occupancy at 26.6KB (v18), VGPR-clamp (v17: spill catastrophe), mega-fusion
// (R7-R9: coop launch dropped under graph capture; sw grid barrier ~100us).
// Residency is pinned ~2 blocks/CU by a non-source-visible cap; all pipes
// <30% busy.  This structure stands as the session optimum.
// ---------------------------------------------------------------------------
__global__ __launch_bounds__(256) void attn_kernel(
    const unsigned short* __restrict__ q_frag, const unsigned short* __restrict__ k_frag,
    const unsigned short* __restrict__ v_frag, unsigned short* __restrict__ o_ws) {
  __shared__ short k_lds[2][8192];    // 2 x (32 kv x 256 d) fragment-major
  __shared__ short p_lds[2][64][40];  // 2 x (64 q x 32 kv)
  __shared__ float l_sh[64];

  const int tid = threadIdx.x;
  const int wid = tid >> 6, lane = tid & 63;
  const int quad = lane >> 4, l16 = lane & 15;
  const int blk = blockIdx.x;
  const int g = blk & 7;                 // XCD (dispatch round-robin heuristic)
  const int qt = (blk >> 3) & 15;        // q tile (64 rows)
  const int bh = g + 8 * (blk >> 7);     // 16 same-bh blocks share one XCD
  const size_t fbase = (size_t)bh * 262144;

  // Q fragments: wave's own 16 q-rows, all 8 d-chunks (coalesced, once).
  bf8 qf[8];
  {
    const unsigned short* qp = q_frag + fbase + (size_t)(qt * 4 + wid) * 4096 + lane * 8;
#pragma unroll
    for (int kc = 0; kc < 8; kc++) qf[kc] = *(const bf8*)(qp + kc * 512);
  }

  const f4 z4 = {0.f, 0.f, 0.f, 0.f};
  f4 Oacc[4][4];  // [mi(d)][nq(q)]: d = wid*64+mi*16+quad*4+reg, q = nq*16+l16
#pragma unroll
  for (int i = 0; i < 4; i++)
#pragma unroll
    for (int j = 0; j < 4; j++) Oacc[i][j] = z4;
  float lpart[4] = {0.f, 0.f, 0.f, 0.f};

  const unsigned short* kdma_src = k_frag + fbase + (size_t)wid * 2048 + lane * 8;
  // prologue: DMA K(0) into buffer 0
#pragma unroll
  for (int jj = 0; jj < 4; jj++)
    gl_lds16(kdma_src + jj * 512, &k_lds[0][wid * 2048 + jj * 512]);
  __syncthreads();

  bf8 vpre0[4], vpre1[4];
  const unsigned short* vbase_p = v_frag + fbase + (size_t)(wid * 4) * 16384 + lane * 8;

#define ATTN_STEP(T, CUR, PRV, VCUR, VPRV)                                     \
  {                                                                            \
    const int t_ = (T);                                                        \
    _Pragma("unroll")                                                          \
    for (int mi = 0; mi < 4; mi++)                                             \
      VCUR[mi] = *(const bf8*)(vbase_p + (size_t)mi * 16384 + (size_t)t_ * 512); \
    f4 Sacc[2];                                                                \
    Sacc[0] = z4; Sacc[1] = z4;                                                \
    _Pragma("unroll")                                                          \
    for (int kc = 0; kc < 8; kc++) {                                           \
      const bf8 aq = qf[kc];                                                   \
      _Pragma("unroll")                                                        \
      for (int ni = 0; ni < 2; ni++) {                                         \
        const bf8 kb = *(const bf8*)(&k_lds[CUR][(ni * 8 + kc) * 512 + lane * 8]); \
        Sacc[ni] = __builtin_amdgcn_mfma_f32_16x16x32_bf16(aq, kb, Sacc[ni], 0, 0, 0); \
      }                                                                        \
    }                                                                          \
    if (t_ < 31) {                                                             \
      _Pragma("unroll")                                                        \
      for (int jj = 0; jj < 4; jj++)                                           \
        gl_lds16(kdma_src + (size_t)(t_ + 1) * 8192 + jj * 512,                \
                 &k_lds[PRV][wid * 2048 + jj * 512]);                          \
    }                                                                          \
    if (t_ > 0) {                                                              \
      bf8 pb[4];                                                               \
      _Pragma("unroll")                                                        \
      for (int nq = 0; nq < 4; nq++)                                           \
        pb[nq] = *(const bf8*)(&p_lds[PRV][nq * 16 + l16][quad * 8]);          \
      _Pragma("unroll")                                                        \
      for (int mi = 0; mi < 4; mi++)                                           \
        _Pragma("unroll")                                                      \
        for (int nq = 0; nq < 4; nq++)                                         \
          Oacc[mi][nq] = __builtin_amdgcn_mfma_f32_16x16x32_bf16(VPRV[mi], pb[nq], Oacc[mi][nq], 0, 0, 0); \
    }                                                                          \
    _Pragma("unroll")                                                          \
    for (int reg = 0; reg < 4; reg++) {                                        \
      const int qrow = wid * 16 + quad * 4 + reg;                              \
      float s = 0.f;                                                           \
      _Pragma("unroll")                                                        \
      for (int ni = 0; ni < 2; ni++) {                                         \
        const float p = exp2f(Sacc[ni][reg]);                                  \
        s += p;                                                                \
        union { float f; uint32_t u; } c;                                      \
        c.f = p;                                                               \
        p_lds[CUR][qrow][ni * 16 + l16] = (short)((c.u + 0x8000u) >> 16);      \
      }                                                                        \
      lpart[reg] += s;                                                         \
    }                                                                          \
    __syncthreads();                                                           \
  }

  for (int tt = 0; tt < 16; tt++) {
    ATTN_STEP(tt * 2, 0, 1, vpre0, vpre1)
    ATTN_STEP(tt * 2 + 1, 1, 0, vpre1, vpre0)
  }
#undef ATTN_STEP

  // ---- drain: PV(31) from buffers of t=31 (CUR was 1)
  {
    bf8 pb[4];
#pragma unroll
    for (int nq = 0; nq < 4; nq++)
      pb[nq] = *(const bf8*)(&p_lds[1][nq * 16 + l16][quad * 8]);
#pragma unroll
    for (int mi = 0; mi < 4; mi++)
#pragma unroll
      for (int nq = 0; nq < 4; nq++)
        Oacc[mi][nq] = __builtin_amdgcn_mfma_f32_16x16x32_bf16(vpre1[mi], pb[nq], Oacc[mi][nq], 0, 0, 0);
  }

  // ---- final l: reduce over 16 kv-col lanes (each q owned by one wave)
#pragma unroll
  for (int reg = 0; reg < 4; reg++) {
    float v = lpart[reg];
    v += __shfl_xor(v, 1, 64);
    v += __shfl_xor(v, 2, 64);
    v += __shfl_xor(v, 4, 64);
    v += __shfl_xor(v, 8, 64);
    if (l16 == 0) l_sh[wid * 16 + quad * 4 + reg] = v;
  }
  __syncthreads();

  // ---- epilogue: O^T[d][q] / l(q) -> o_ws [B,S,H*256]
  const int b = bh >> 3, h = bh & 7;
#pragma unroll
  for (int nq = 0; nq < 4; nq++) {
    const int q = nq * 16 + l16;
    const float inv = 1.f / l_sh[q];
    const size_t base = ((size_t)b * SEQ + qt * 64 + q) * (NH * DM) + h * DM + wid * 64;
#pragma unroll
    for (int mi = 0; mi < 4; mi++) {
      short4 s4;
      s4.x = (short)f2bf(Oacc[mi][nq][0] * inv);
      s4.y = (short)f2bf(Oacc[mi][nq][1] * inv);
      s4.z = (short)f2bf(Oacc[mi][nq][2] * inv);
      s4.w = (short)f2bf(Oacc[mi][nq][3] * inv);
      *(short4*)(o_ws + base + mi * 16 + quad * 4) = s4;
    }
  }
}

// ---------------------------------------------------------------------------
// Kernel 3: output projection.  BM=32, BN=64, BK=128, grid (128,4).  (R5-exact)
// ---------------------------------------------------------------------------
__global__ __launch_bounds__(256) void outproj_kernel(
    const unsigned short* __restrict__ o_ws, const unsigned short* __restrict__ WoT,
    const float* __restrict__ bo, float* __restrict__ out) {
  __shared__ short a_lds[32][136];
  __shared__ short b_lds[64][136];

  const int tid = threadIdx.x;
  const int wid = tid >> 6, lane = tid & 63;
  const int quad = lane >> 4, l16 = lane & 15;
  const int wm = wid & 1, wn = wid >> 1;
  const int m0 = blockIdx.x * 32, n0 = blockIdx.y * 64;

  const f4 z4 = {0.f, 0.f, 0.f, 0.f};
  f4 acc[2];
#pragma unroll
  for (int i = 0; i < 2; i++) acc[i] = z4;

  const int ch = tid & 15, row = tid >> 4;
  for (int ko = 0; ko < 16; ko++) {
    const int k0 = ko * 128;
#pragma unroll
    for (int rb = 0; rb < 2; rb++) {
      int r = row + rb * 16;
      *(bf8*)(&a_lds[r][ch * 8]) = *(const bf8*)(o_ws + (size_t)(m0 + r) * 2048 + k0 + ch * 8);
    }
#pragma unroll
    for (int rb = 0; rb < 4; rb++) {
      int r = row + rb * 16;
      *(bf8*)(&b_lds[r][ch * 8]) = *(const bf8*)(WoT + (size_t)(n0 + r) * 2048 + k0 + ch * 8);
    }
    __syncthreads();
#pragma unroll
    for (int kc = 0; kc < 4; kc++) {
      const bf8 af = *(const bf8*)(&a_lds[wm * 16 + l16][kc * 32 + quad * 8]);
      bf8 bfv[2];
#pragma unroll
      for (int ni = 0; ni < 2; ni++)
        bfv[ni] = *(const bf8*)(&b_lds[wn * 32 + ni * 16 + l16][kc * 32 + quad * 8]);
#pragma unroll
      for (int ni = 0; ni < 2; ni++)
        acc[ni] = __builtin_amdgcn_mfma_f32_16x16x32_bf16(af, bfv[ni], acc[ni], 0, 0, 0);
    }
    __syncthreads();
  }
#pragma unroll
  for (int ni = 0; ni < 2; ni++) {
    const int n = n0 + wn * 32 + ni * 16 + l16;
    const float bv = bo[n];
#pragma unroll
    for (int reg = 0; reg < 4; reg++) {
      const int m = m0 + wm * 16 + quad * 4 + reg;
      out[(size_t)m * DM + n] = acc[ni][reg] + bv;
    }
  }
}

// ---------------------------------------------------------------------------
extern "C" void kernel_launch(void* const* d_in, const int* in_sizes, int n_in,
                              void* d_out, int out_size, void* d_ws, size_t ws_size,
                              hipStream_t stream) {
  const float* Q  = (const float*)d_in[0];
  const float* K  = (const float*)d_in[1];
  const float* V  = (const float*)d_in[2];
  const float* Wq = (const float*)d_in[3];
  const float* bq = (const float*)d_in[4];
  const float* Wk = (const float*)d_in[5];
  const float* bk = (const float*)d_in[6];
  const float* Wv = (const float*)d_in[7];
  const float* bv = (const float*)d_in[8];
  const float* Wo = (const float*)d_in[9];
  const float* bo = (const float*)d_in[10];
  float* out = (float*)d_out;

  char* ws = (char*)d_ws;
  const size_t QS = (size_t)NB * NH * SEQ * DM * 2;  // 16 MiB each
  unsigned short* q_frag = (unsigned short*)(ws);
  unsigned short* k_frag = (unsigned short*)(ws + QS);
  unsigned short* v_frag = (unsigned short*)(ws + 2 * QS);
  unsigned short* o_ws   = (unsigned short*)(ws + 3 * QS);
  const size_t WT = (size_t)2048 * 256 * 2;  // 1 MiB each
  unsigned short* Wt3 = (unsigned short*)(ws + 4 * QS);           // 3 MiB
  unsigned short* WoT = (unsigned short*)(ws + 4 * QS + 3 * WT);  // 1 MiB
  // Xbf (6 MiB) aliases o_ws: proj reads it before attn overwrites o_ws.
  unsigned short* Xbf = o_ws;

  prep_kernel<<<dim3(1024, 7), 256, 0, stream>>>(Wq, Wk, Wv, Wo, Q, K, V,
                                                 Wt3, WoT, Xbf);
  proj_kernel<<<dim3(32, 16, 3), 256, 0, stream>>>(Xbf, Wt3, bq, bk, bv,
                                                   q_frag, k_frag, v_frag);
  attn_kernel<<<512, 256, 0, stream>>>(q_frag, k_frag, v_frag, o_ws);
  outproj_kernel<<<dim3(128, 4), 256, 0, stream>>>(o_ws, WoT, bo, out);
}